// Round 18
// baseline (115.956 us; speedup 1.0000x reference)
//
#include <hip/hip_runtime.h>
#include <hip/hip_bf16.h>
#include <math.h>
#include <stdint.h>

#define NBR 8
#define SDIM 64
#define DDIM 1024
#define BROWS 16384
#define CAP 16384
#define CSTRIDE 32   // count[] padded: one 128B cache line per counter

typedef __attribute__((ext_vector_type(8))) short bf16x8;
typedef __attribute__((ext_vector_type(4))) float f32x4;

__device__ __forceinline__ ushort f2b(float f) {
  union { __hip_bfloat16 h; ushort u; } cv;
  cv.h = __float2bfloat16(f);
  return cv.u;
}

// ---------------- threefry2x32, key = (0, 1234), JAX-exact ----------------
__device__ __forceinline__ void tf2x32(uint32_t& x0, uint32_t& x1) {
  const uint32_t k0 = 0u, k1 = 1234u;
  const uint32_t ks2 = k0 ^ k1 ^ 0x1BD11BDAu;
#define TFR(r) { x0 += x1; x1 = (x1 << (r)) | (x1 >> (32 - (r))); x1 ^= x0; }
  x0 += k0; x1 += k1;
  TFR(13) TFR(15) TFR(26) TFR(6)
  x0 += k1;  x1 += ks2 + 1u;
  TFR(17) TFR(29) TFR(16) TFR(24)
  x0 += ks2; x1 += k0 + 2u;
  TFR(13) TFR(15) TFR(26) TFR(6)
  x0 += k0;  x1 += k1 + 3u;
  TFR(17) TFR(29) TFR(16) TFR(24)
  x0 += k1;  x1 += ks2 + 4u;
  TFR(13) TFR(15) TFR(26) TFR(6)
  x0 += ks2; x1 += k0 + 5u;
#undef TFR
}

// ---------------- K1: fold v[n][d] = sum_s W_in[n][d][s]*W_sw[n][s] (fp64) ----
__global__ __launch_bounds__(256) void k_fold(
    const float* __restrict__ W_in, const float* __restrict__ b_in,
    const float* __restrict__ W_sw, const float* __restrict__ b_sw,
    double* __restrict__ v, double* __restrict__ c, int* __restrict__ count) {
  int gid = blockIdx.x * 256 + threadIdx.x;
  if (gid < NBR * DDIM) {
    int n = gid >> 10, d = gid & 1023;
    const float* wi = W_in + ((size_t)n * DDIM + d) * SDIM;
    const float* ws = W_sw + n * SDIM;
    double acc = 0.0;
    for (int s = 0; s < SDIM; s++) acc += (double)wi[s] * (double)ws[s];
    v[gid] = acc;
  } else if (gid < NBR * DDIM + NBR) {
    int n = gid - NBR * DDIM;
    const float* bi = b_in + n * SDIM;
    const float* ws = W_sw + n * SDIM;
    double acc = (double)b_sw[n];
    for (int s = 0; s < SDIM; s++) acc += (double)bi[s] * (double)ws[s];
    c[n] = acc;
  } else if (gid < NBR * DDIM + 2 * NBR) {
    count[(gid - NBR * DDIM - NBR) * CSTRIDE] = 0;
  }
}

// ---------------- K2a: partial logits, 4-way d-split + optional xb write ----
// (round-9-verified compute; optionally emits xb = f2b(relu(x)) bf16 so k_h
// can skip its A-staging — each (row-group, q) block covers its slice once)
__global__ __launch_bounds__(256) void k_logits_part(
    const float* __restrict__ x, const double* __restrict__ vg,
    double* __restrict__ part, ushort* __restrict__ xb, int use_xb) {
  __shared__ float xs[32][132];    // 16896 B
  __shared__ double vsd[8][130];   //  8320 B
  int t = threadIdx.x;
  int r = t >> 3, n = t & 7;
  int row0 = (blockIdx.x >> 2) * 32;
  int q = blockIdx.x & 3;
  int d0 = q * 256;
  int lxr = t >> 3, lxc = (t & 7) * 16;
  int lvn = t >> 5, lvd = (t & 31) * 4;
  const float* xlp = x + (size_t)(row0 + lxr) * DDIM + d0 + lxc;
  const double* vlp = vg + (size_t)lvn * DDIM + d0 + lvd;
  double acc0 = 0.0, acc1 = 0.0, acc2 = 0.0, acc3 = 0.0;
  for (int kt = 0; kt < 256; kt += 128) {
    __syncthreads();
    {  // stage relu(x) tile, float4 stores (+ optional bf16 xb write)
      float4 a0 = *(const float4*)&xlp[kt + 0];
      float4 a1 = *(const float4*)&xlp[kt + 4];
      float4 a2 = *(const float4*)&xlp[kt + 8];
      float4 a3 = *(const float4*)&xlp[kt + 12];
      a0.x = fmaxf(a0.x, 0.f); a0.y = fmaxf(a0.y, 0.f);
      a0.z = fmaxf(a0.z, 0.f); a0.w = fmaxf(a0.w, 0.f);
      a1.x = fmaxf(a1.x, 0.f); a1.y = fmaxf(a1.y, 0.f);
      a1.z = fmaxf(a1.z, 0.f); a1.w = fmaxf(a1.w, 0.f);
      a2.x = fmaxf(a2.x, 0.f); a2.y = fmaxf(a2.y, 0.f);
      a2.z = fmaxf(a2.z, 0.f); a2.w = fmaxf(a2.w, 0.f);
      a3.x = fmaxf(a3.x, 0.f); a3.y = fmaxf(a3.y, 0.f);
      a3.z = fmaxf(a3.z, 0.f); a3.w = fmaxf(a3.w, 0.f);
      float* dst = &xs[lxr][lxc];
      *(float4*)&dst[0]  = a0;
      *(float4*)&dst[4]  = a1;
      *(float4*)&dst[8]  = a2;
      *(float4*)&dst[12] = a3;
      if (use_xb) {
        ushort ub[16];
        ub[0]=f2b(a0.x); ub[1]=f2b(a0.y); ub[2]=f2b(a0.z); ub[3]=f2b(a0.w);
        ub[4]=f2b(a1.x); ub[5]=f2b(a1.y); ub[6]=f2b(a1.z); ub[7]=f2b(a1.w);
        ub[8]=f2b(a2.x); ub[9]=f2b(a2.y); ub[10]=f2b(a2.z); ub[11]=f2b(a2.w);
        ub[12]=f2b(a3.x); ub[13]=f2b(a3.y); ub[14]=f2b(a3.z); ub[15]=f2b(a3.w);
        ushort* xd = xb + (size_t)(row0 + lxr) * DDIM + d0 + kt + lxc;
        *(bf16x8*)&xd[0] = *(bf16x8*)&ub[0];
        *(bf16x8*)&xd[8] = *(bf16x8*)&ub[8];
      }
    }
    {  // stage v chunk
      double2 v0 = *(const double2*)&vlp[kt];
      double2 v1 = *(const double2*)&vlp[kt + 2];
      *(double2*)&vsd[lvn][lvd]     = v0;
      *(double2*)&vsd[lvn][lvd + 2] = v1;
    }
    __syncthreads();
#pragma unroll
    for (int d = 0; d < 128; d += 4) {
      float4 xv = *(const float4*)&xs[r][d];
      double2 va = *(const double2*)&vsd[n][d];
      double2 vb = *(const double2*)&vsd[n][d + 2];
      acc0 = fma((double)xv.x, va.x, acc0);
      acc1 = fma((double)xv.y, va.y, acc1);
      acc2 = fma((double)xv.z, vb.x, acc2);
      acc3 = fma((double)xv.w, vb.y, acc3);
    }
  }
  part[((size_t)q * BROWS + row0 + r) * 8 + n] =
      (acc0 + acc1) + (acc2 + acc3);
}

// ---------------- K2b: sum partials + gumbel + argmax + compaction ----------
// (round-15-verified, unchanged)
__global__ __launch_bounds__(256) void k_gumbel(
    const double* __restrict__ part, const double* __restrict__ cg_,
    float* __restrict__ out_logits, float* __restrict__ out_index,
    float* __restrict__ out_hard, int* __restrict__ count,
    int* __restrict__ order) {
  __shared__ int hcnt[8];
  __shared__ int hbase[8];
  int t = threadIdx.x;
  if (t < 8) hcnt[t] = 0;
  __syncthreads();
  int n = t & 7;
  int lw = t & 63;
  int rbase = blockIdx.x * 64;
  int best2[2], lpos2[2];
#pragma unroll
  for (int rr = 0; rr < 2; rr++) {
    int row = rbase + rr * 32 + (t >> 3);
    size_t idx = (size_t)row * 8 + n;
    double p0 = part[idx];
    double p1 = part[(size_t)BROWS * 8 + idx];
    double p2 = part[(size_t)2 * BROWS * 8 + idx];
    double p3 = part[(size_t)3 * BROWS * 8 + idx];
    double lg = ((p0 + p1) + (p2 + p3)) + cg_[n];
    uint32_t f = (uint32_t)row * 8u + (uint32_t)n;
    uint32_t c0 = 0u, c1 = f;
    tf2x32(c0, c1);
    uint32_t bits = c0 ^ c1;
    float u = __uint_as_float(0x3F800000u | (bits >> 9)) - 1.0f;
    float ef = (float)(-log1p(-(double)u));
    double gn = -log((double)ef + 1e-20);
    double gv = lg + gn;                    // TAU = 1
    double m = gv;
    m = fmax(m, __shfl_xor(m, 1));
    m = fmax(m, __shfl_xor(m, 2));
    m = fmax(m, __shfl_xor(m, 4));
    unsigned long long mask = __ballot(gv == m);
    int best = __builtin_ctzll((mask >> (lw & 56)) & 0xFFull);
    out_logits[idx] = (float)lg;
    out_hard[idx] = (n == best) ? 1.0f : 0.0f;
    int lp = 0;
    if (n == 0) {
      out_index[row] = (float)best;
      lp = atomicAdd(&hcnt[best], 1);
    }
    best2[rr] = best;
    lpos2[rr] = lp;
  }
  __syncthreads();
  if (t < 8) hbase[t] = atomicAdd(&count[t * CSTRIDE], hcnt[t]);
  __syncthreads();
  if (n == 0) {
#pragma unroll
    for (int rr = 0; rr < 2; rr++) {
      int row = rbase + rr * 32 + (t >> 3);
      order[best2[rr] * CAP + hbase[best2[rr]] + lpos2[rr]] = row;
    }
  }
}

// ---------------- K3a: h = relu(x) @ W_in[sel] + b_in  (bf16 out) -----------
// 16-row segments (round-16). If use_xb: A-fragments gathered directly from
// xb (bit-identical to the staged A_lds bits) — no A staging, no f2b.
__global__ __launch_bounds__(256) void k_h(
    const float* __restrict__ x, const float* __restrict__ W_in,
    const float* __restrict__ b_in, const int* __restrict__ count,
    const int* __restrict__ order, ushort* __restrict__ h_ws,
    const ushort* __restrict__ xb, int use_xb) {
  __shared__ int rows[16];
  __shared__ __align__(16) ushort A_lds[16 * 128];   //  4 KB (fallback path)
  __shared__ __align__(16) ushort Bi_lds[64 * 128];  // 16 KB
  int t = threadIdx.x;
  int n = blockIdx.x >> 8;
  int seg = blockIdx.x & 255;
  int cnt = count[n * CSTRIDE];
  int base = seg * 16;
  if (base >= cnt) return;
  if (t < 16) rows[t] = (base + t < cnt) ? order[n * CAP + base + t] : -1;
  __syncthreads();
  const int l = t & 63, w = t >> 6;
  const int fr = l & 15, fg = l >> 4;
  const int swz = (fr & 7) << 4;
  const int sxr = t >> 4, sxc = (t & 15) * 8;   // x: row 0..15, 8 floats
  const int swc = t & 63, swq = t >> 6;         // W: col 0..63, k-quarter
  int growx = rows[sxr];
  bool livex = growx >= 0;
  const float* xsrc = x + (size_t)(livex ? growx : 0) * DDIM + sxc;
  const float* Wn = W_in + (size_t)n * DDIM * SDIM;
  // direct-gather A source (use_xb path)
  const int hrow = rows[fr];
  const bool hlive = hrow >= 0;
  const ushort* xrow = xb + (size_t)(hlive ? hrow : 0) * DDIM;
  f32x4 acc = {};
  for (int kt = 0; kt < DDIM; kt += 128) {
    if (!use_xb) {  // stage A: relu(x) -> bf16, swizzled (fallback)
      ushort ub[8];
#pragma unroll
      for (int j = 0; j < 2; j++) {
        float4 v = *(const float4*)&xsrc[kt + j * 4];
        ub[j*4+0] = livex ? f2b(fmaxf(v.x, 0.f)) : (ushort)0;
        ub[j*4+1] = livex ? f2b(fmaxf(v.y, 0.f)) : (ushort)0;
        ub[j*4+2] = livex ? f2b(fmaxf(v.z, 0.f)) : (ushort)0;
        ub[j*4+3] = livex ? f2b(fmaxf(v.w, 0.f)) : (ushort)0;
      }
      int byte = sxr * 256 + ((sxc * 2) ^ ((sxr & 7) << 4));
      *(bf16x8*)((char*)A_lds + byte) = *(bf16x8*)&ub[0];
    }
    {  // stage B: W_in slab transposed (coalesced read along cols)
      ushort ub[32];
#pragma unroll
      for (int j = 0; j < 32; j++)
        ub[j] = f2b(Wn[(size_t)(kt + swq * 32 + j) * SDIM + swc]);
#pragma unroll
      for (int jj = 0; jj < 4; jj++) {
        int byte = swc * 256 + ((swq * 64 + jj * 16) ^ ((swc & 7) << 4));
        *(bf16x8*)((char*)Bi_lds + byte) = *(bf16x8*)&ub[jj * 8];
      }
    }
    __syncthreads();
#pragma unroll
    for (int ks = 0; ks < 4; ks++) {
      bf16x8 bf = *(const bf16x8*)((const char*)Bi_lds +
                    (w * 16 + fr) * 256 + ((ks * 64 + fg * 16) ^ swz));
      bf16x8 af;
      if (use_xb) {
        af = bf16x8{};
        if (hlive) af = *(const bf16x8*)&xrow[kt + ks * 32 + fg * 8];
      } else {
        af = *(const bf16x8*)((const char*)A_lds +
               fr * 256 + ((ks * 64 + fg * 16) ^ swz));
      }
      acc = __builtin_amdgcn_mfma_f32_16x16x32_bf16(af, bf, acc, 0, 0, 0);
    }
    __syncthreads();
  }
  int col = w * 16 + fr;
  float bb = b_in[n * SDIM + col];
#pragma unroll
  for (int r = 0; r < 4; r++) {
    int grow = rows[fg * 4 + r];
    if (grow >= 0)
      h_ws[(size_t)grow * SDIM + col] = f2b(acc[r] + bb);
  }
}

// ---------------- K3b: out = x + h @ W_out[sel] + b_out ---------------------
// (round-17-verified: direct h gather, Bo/Ot arena; grid 4096)
__global__ __launch_bounds__(256) void k_out2(
    const float* __restrict__ x, const float* __restrict__ W_out,
    const float* __restrict__ b_out, const int* __restrict__ count,
    const int* __restrict__ order, const ushort* __restrict__ h_ws,
    float* __restrict__ out) {
  __shared__ int rows[64];
  __shared__ __align__(16) char arena[64 * 68 * 4];  // 17408 B: Bo (16384) / Ot
  ushort* Bo_lds = (ushort*)arena;
  float* Ot = (float*)arena;
  int t = threadIdx.x;
  int n = blockIdx.x >> 9;
  int seg = (blockIdx.x >> 3) & 63;
  int cc = (blockIdx.x & 7) * 128;
  int cnt = count[n * CSTRIDE];
  int base = seg * 64;
  if (base >= cnt) return;
  if (t < 64) rows[t] = (base + t < cnt) ? order[n * CAP + base + t] : -1;
  __syncthreads();
  const int l = t & 63, w = t >> 6;
  const int fr = l & 15, fg = l >> 4;
  const int swz = (fr & 7) << 4;
  const int hgrow = rows[w * 16 + fr];
  bf16x8 af0 = {}, af1 = {};
  if (hgrow >= 0) {
    const ushort* hp = h_ws + (size_t)hgrow * SDIM + fg * 8;
    af0 = *(const bf16x8*)hp;
    af1 = *(const bf16x8*)(hp + 32);
  }
  {  // stage W_out chunk transposed (inline f2b — coalesced)
    const float* Wo = W_out + (size_t)n * SDIM * DDIM;
    int scol = t & 127, sh = t >> 7;
    ushort ub[32];
#pragma unroll
    for (int j = 0; j < 32; j++)
      ub[j] = f2b(Wo[(size_t)(sh * 32 + j) * DDIM + cc + scol]);
#pragma unroll
    for (int jj = 0; jj < 4; jj++) {
      int byte = scol * 128 + ((sh * 64 + jj * 16) ^ ((scol & 7) << 4));
      *(bf16x8*)((char*)Bo_lds + byte) = *(bf16x8*)&ub[jj * 8];
    }
  }
  __syncthreads();
  f32x4 acc2[8] = {};
#pragma unroll
  for (int ks = 0; ks < 2; ks++) {
    bf16x8 af = ks ? af1 : af0;
#pragma unroll
    for (int nt = 0; nt < 8; nt++) {
      bf16x8 bf = *(const bf16x8*)((const char*)Bo_lds +
                    (nt * 16 + fr) * 128 + ((ks * 64 + fg * 16) ^ swz));
      acc2[nt] = __builtin_amdgcn_mfma_f32_16x16x32_bf16(af, bf, acc2[nt], 0, 0, 0);
    }
  }
  const float* bo = b_out + n * DDIM + cc;
#pragma unroll
  for (int nt = 0; nt < 8; nt++) {
    float bov = bo[nt * 16 + fr];
#pragma unroll
    for (int r = 0; r < 4; r++) acc2[nt][r] += bov;
  }
  const int orow = t >> 2;            // 0..63
  const int ocol = (t & 3) * 16;      // 0,16,32,48
  const int ogrow = rows[orow];
#pragma unroll
  for (int hh = 0; hh < 2; hh++) {
    __syncthreads();
#pragma unroll
    for (int ntl = 0; ntl < 4; ntl++) {
      int col = ntl * 16 + fr;
#pragma unroll
      for (int r = 0; r < 4; r++)
        Ot[(w * 16 + fg * 4 + r) * 68 + col] = acc2[hh * 4 + ntl][r];
    }
    __syncthreads();
    if (ogrow >= 0) {
      const float* xp = x + (size_t)ogrow * DDIM + cc + hh * 64 + ocol;
      float* op = out + (size_t)ogrow * DDIM + cc + hh * 64 + ocol;
#pragma unroll
      for (int j = 0; j < 4; j++) {
        float4 xx = *(const float4*)&xp[j * 4];
        float4 oo = *(const float4*)&Ot[orow * 68 + ocol + j * 4];
        oo.x += xx.x; oo.y += xx.y; oo.z += xx.z; oo.w += xx.w;
        *(float4*)&op[j * 4] = oo;
      }
    }
  }
}

extern "C" void kernel_launch(void* const* d_in, const int* in_sizes, int n_in,
                              void* d_out, int out_size, void* d_ws, size_t ws_size,
                              hipStream_t stream) {
  const float* x    = (const float*)d_in[0];
  const float* W_in = (const float*)d_in[1];
  const float* b_in = (const float*)d_in[2];
  const float* W_sw = (const float*)d_in[3];
  const float* b_sw = (const float*)d_in[4];
  const float* W_out= (const float*)d_in[5];
  const float* b_out= (const float*)d_in[6];
  float* out0  = (float*)d_out;
  float* ylog  = out0 + (size_t)BROWS * DDIM;
  float* yidx  = ylog + (size_t)BROWS * NBR;
  float* yhard = yidx + (size_t)BROWS;
  char* ws = (char*)d_ws;
  double* v    = (double*)ws;                              // 65536 B
  double* c    = (double*)(ws + 65536);                    // 64 B
  int* count   = (int*)(ws + 65600);                       // 1024 B (8 x 128B)
  int* order   = (int*)(ws + 66624);                       // 524288 B
  ushort* h_ws = (ushort*)(ws + 590912);                   // 2 MB
  double* part = (double*)(ws + 2688064);                  // 4 MB
  size_t xb_off = 2688064 + 4194304;                       // 6882368
  int use_xb = (ws_size >= xb_off + (size_t)BROWS * DDIM * 2) ? 1 : 0;
  ushort* xb = (ushort*)(ws + xb_off);                     // 33.5 MB if avail
  hipLaunchKernelGGL(k_fold, dim3(33), dim3(256), 0, stream,
                     W_in, b_in, W_sw, b_sw, v, c, count);
  hipLaunchKernelGGL(k_logits_part, dim3(2048), dim3(256), 0, stream,
                     x, v, part, xb, use_xb);
  hipLaunchKernelGGL(k_gumbel, dim3(256), dim3(256), 0, stream,
                     part, c, ylog, yidx, yhard, count, order);
  hipLaunchKernelGGL(k_h, dim3(2048), dim3(256), 0, stream,
                     x, W_in, b_in, count, order, h_ws, xb, use_xb);
  hipLaunchKernelGGL(k_out2, dim3(4096), dim3(256), 0, stream,
                     x, W_out, b_out, count, order, h_ws, out0);
}

// Round 19
// 102.063 us; speedup vs baseline: 1.1361x; 1.1361x over previous
//
#include <hip/hip_runtime.h>
#include <hip/hip_bf16.h>
#include <math.h>
#include <stdint.h>

#define NBR 8
#define SDIM 64
#define DDIM 1024
#define BROWS 16384
#define CAP 16384
#define CSTRIDE 32   // count[] padded: one 128B cache line per counter

typedef __attribute__((ext_vector_type(8))) short bf16x8;
typedef __attribute__((ext_vector_type(4))) float f32x4;

__device__ __forceinline__ ushort f2b(float f) {
  union { __hip_bfloat16 h; ushort u; } cv;
  cv.h = __float2bfloat16(f);
  return cv.u;
}

// ---------------- threefry2x32, key = (0, 1234), JAX-exact ----------------
__device__ __forceinline__ void tf2x32(uint32_t& x0, uint32_t& x1) {
  const uint32_t k0 = 0u, k1 = 1234u;
  const uint32_t ks2 = k0 ^ k1 ^ 0x1BD11BDAu;
#define TFR(r) { x0 += x1; x1 = (x1 << (r)) | (x1 >> (32 - (r))); x1 ^= x0; }
  x0 += k0; x1 += k1;
  TFR(13) TFR(15) TFR(26) TFR(6)
  x0 += k1;  x1 += ks2 + 1u;
  TFR(17) TFR(29) TFR(16) TFR(24)
  x0 += ks2; x1 += k0 + 2u;
  TFR(13) TFR(15) TFR(26) TFR(6)
  x0 += k0;  x1 += k1 + 3u;
  TFR(17) TFR(29) TFR(16) TFR(24)
  x0 += k1;  x1 += ks2 + 4u;
  TFR(13) TFR(15) TFR(26) TFR(6)
  x0 += ks2; x1 += k0 + 5u;
#undef TFR
}

// ---------------- K1: fold v[n][d] = sum_s W_in[n][d][s]*W_sw[n][s] (fp64) ----
__global__ __launch_bounds__(256) void k_fold(
    const float* __restrict__ W_in, const float* __restrict__ b_in,
    const float* __restrict__ W_sw, const float* __restrict__ b_sw,
    double* __restrict__ v, double* __restrict__ c, int* __restrict__ count) {
  int gid = blockIdx.x * 256 + threadIdx.x;
  if (gid < NBR * DDIM) {
    int n = gid >> 10, d = gid & 1023;
    const float* wi = W_in + ((size_t)n * DDIM + d) * SDIM;
    const float* ws = W_sw + n * SDIM;
    double acc = 0.0;
    for (int s = 0; s < SDIM; s++) acc += (double)wi[s] * (double)ws[s];
    v[gid] = acc;
  } else if (gid < NBR * DDIM + NBR) {
    int n = gid - NBR * DDIM;
    const float* bi = b_in + n * SDIM;
    const float* ws = W_sw + n * SDIM;
    double acc = (double)b_sw[n];
    for (int s = 0; s < SDIM; s++) acc += (double)bi[s] * (double)ws[s];
    c[n] = acc;
  } else if (gid < NBR * DDIM + 2 * NBR) {
    count[(gid - NBR * DDIM - NBR) * CSTRIDE] = 0;
  }
}

// ---------------- K2a: partial logits, 4-way d-split ------------------------
// (round-9-verified, unchanged)
__global__ __launch_bounds__(256) void k_logits_part(
    const float* __restrict__ x, const double* __restrict__ vg,
    double* __restrict__ part) {
  __shared__ float xs[32][132];    // 16896 B
  __shared__ double vsd[8][130];   //  8320 B
  int t = threadIdx.x;
  int r = t >> 3, n = t & 7;
  int row0 = (blockIdx.x >> 2) * 32;
  int q = blockIdx.x & 3;
  int d0 = q * 256;
  int lxr = t >> 3, lxc = (t & 7) * 16;
  int lvn = t >> 5, lvd = (t & 31) * 4;
  const float* xlp = x + (size_t)(row0 + lxr) * DDIM + d0 + lxc;
  const double* vlp = vg + (size_t)lvn * DDIM + d0 + lvd;
  double acc0 = 0.0, acc1 = 0.0, acc2 = 0.0, acc3 = 0.0;
  for (int kt = 0; kt < 256; kt += 128) {
    __syncthreads();
    {  // stage relu(x) tile, float4 stores
      float4 a0 = *(const float4*)&xlp[kt + 0];
      float4 a1 = *(const float4*)&xlp[kt + 4];
      float4 a2 = *(const float4*)&xlp[kt + 8];
      float4 a3 = *(const float4*)&xlp[kt + 12];
      a0.x = fmaxf(a0.x, 0.f); a0.y = fmaxf(a0.y, 0.f);
      a0.z = fmaxf(a0.z, 0.f); a0.w = fmaxf(a0.w, 0.f);
      a1.x = fmaxf(a1.x, 0.f); a1.y = fmaxf(a1.y, 0.f);
      a1.z = fmaxf(a1.z, 0.f); a1.w = fmaxf(a1.w, 0.f);
      a2.x = fmaxf(a2.x, 0.f); a2.y = fmaxf(a2.y, 0.f);
      a2.z = fmaxf(a2.z, 0.f); a2.w = fmaxf(a2.w, 0.f);
      a3.x = fmaxf(a3.x, 0.f); a3.y = fmaxf(a3.y, 0.f);
      a3.z = fmaxf(a3.z, 0.f); a3.w = fmaxf(a3.w, 0.f);
      float* dst = &xs[lxr][lxc];
      *(float4*)&dst[0]  = a0;
      *(float4*)&dst[4]  = a1;
      *(float4*)&dst[8]  = a2;
      *(float4*)&dst[12] = a3;
    }
    {  // stage v chunk
      double2 v0 = *(const double2*)&vlp[kt];
      double2 v1 = *(const double2*)&vlp[kt + 2];
      *(double2*)&vsd[lvn][lvd]     = v0;
      *(double2*)&vsd[lvn][lvd + 2] = v1;
    }
    __syncthreads();
#pragma unroll
    for (int d = 0; d < 128; d += 4) {
      float4 xv = *(const float4*)&xs[r][d];
      double2 va = *(const double2*)&vsd[n][d];
      double2 vb = *(const double2*)&vsd[n][d + 2];
      acc0 = fma((double)xv.x, va.x, acc0);
      acc1 = fma((double)xv.y, va.y, acc1);
      acc2 = fma((double)xv.z, vb.x, acc2);
      acc3 = fma((double)xv.w, vb.y, acc3);
    }
  }
  part[((size_t)q * BROWS + row0 + r) * 8 + n] =
      (acc0 + acc1) + (acc2 + acc3);
}

// ---------------- K2b: sum partials + gumbel + argmax + compaction ----------
// (round-15-verified, unchanged)
__global__ __launch_bounds__(256) void k_gumbel(
    const double* __restrict__ part, const double* __restrict__ cg_,
    float* __restrict__ out_logits, float* __restrict__ out_index,
    float* __restrict__ out_hard, int* __restrict__ count,
    int* __restrict__ order) {
  __shared__ int hcnt[8];
  __shared__ int hbase[8];
  int t = threadIdx.x;
  if (t < 8) hcnt[t] = 0;
  __syncthreads();
  int n = t & 7;
  int lw = t & 63;
  int rbase = blockIdx.x * 64;
  int best2[2], lpos2[2];
#pragma unroll
  for (int rr = 0; rr < 2; rr++) {
    int row = rbase + rr * 32 + (t >> 3);
    size_t idx = (size_t)row * 8 + n;
    double p0 = part[idx];
    double p1 = part[(size_t)BROWS * 8 + idx];
    double p2 = part[(size_t)2 * BROWS * 8 + idx];
    double p3 = part[(size_t)3 * BROWS * 8 + idx];
    double lg = ((p0 + p1) + (p2 + p3)) + cg_[n];
    uint32_t f = (uint32_t)row * 8u + (uint32_t)n;
    uint32_t c0 = 0u, c1 = f;
    tf2x32(c0, c1);
    uint32_t bits = c0 ^ c1;
    float u = __uint_as_float(0x3F800000u | (bits >> 9)) - 1.0f;
    float ef = (float)(-log1p(-(double)u));
    double gn = -log((double)ef + 1e-20);
    double gv = lg + gn;                    // TAU = 1
    double m = gv;
    m = fmax(m, __shfl_xor(m, 1));
    m = fmax(m, __shfl_xor(m, 2));
    m = fmax(m, __shfl_xor(m, 4));
    unsigned long long mask = __ballot(gv == m);
    int best = __builtin_ctzll((mask >> (lw & 56)) & 0xFFull);
    out_logits[idx] = (float)lg;
    out_hard[idx] = (n == best) ? 1.0f : 0.0f;
    int lp = 0;
    if (n == 0) {
      out_index[row] = (float)best;
      lp = atomicAdd(&hcnt[best], 1);
    }
    best2[rr] = best;
    lpos2[rr] = lp;
  }
  __syncthreads();
  if (t < 8) hbase[t] = atomicAdd(&count[t * CSTRIDE], hcnt[t]);
  __syncthreads();
  if (n == 0) {
#pragma unroll
    for (int rr = 0; rr < 2; rr++) {
      int row = rbase + rr * 32 + (t >> 3);
      order[best2[rr] * CAP + hbase[best2[rr]] + lpos2[rr]] = row;
    }
  }
}

// ---------------- K3a: h = relu(x) @ W_in[sel] + b_in  (bf16 out) -----------
// (round-16-verified, 16-row segments, staged A)
__global__ __launch_bounds__(256) void k_h(
    const float* __restrict__ x, const float* __restrict__ W_in,
    const float* __restrict__ b_in, const int* __restrict__ count,
    const int* __restrict__ order, ushort* __restrict__ h_ws) {
  __shared__ int rows[16];
  __shared__ __align__(16) ushort A_lds[16 * 128];   //  4 KB
  __shared__ __align__(16) ushort Bi_lds[64 * 128];  // 16 KB
  int t = threadIdx.x;
  int n = blockIdx.x >> 8;
  int seg = blockIdx.x & 255;
  int cnt = count[n * CSTRIDE];
  int base = seg * 16;
  if (base >= cnt) return;
  if (t < 16) rows[t] = (base + t < cnt) ? order[n * CAP + base + t] : -1;
  __syncthreads();
  const int l = t & 63, w = t >> 6;
  const int fr = l & 15, fg = l >> 4;
  const int swz = (fr & 7) << 4;
  const int sxr = t >> 4, sxc = (t & 15) * 8;   // x: row 0..15, 8 floats
  const int swc = t & 63, swq = t >> 6;         // W: col 0..63, k-quarter
  int growx = rows[sxr];
  bool livex = growx >= 0;
  const float* xsrc = x + (size_t)(livex ? growx : 0) * DDIM + sxc;
  const float* Wn = W_in + (size_t)n * DDIM * SDIM;
  f32x4 acc = {};
  for (int kt = 0; kt < DDIM; kt += 128) {
    {  // stage A: relu(x) -> bf16, swizzled (8 floats -> one bf16x8 store)
      ushort ub[8];
#pragma unroll
      for (int j = 0; j < 2; j++) {
        float4 v = *(const float4*)&xsrc[kt + j * 4];
        ub[j*4+0] = livex ? f2b(fmaxf(v.x, 0.f)) : (ushort)0;
        ub[j*4+1] = livex ? f2b(fmaxf(v.y, 0.f)) : (ushort)0;
        ub[j*4+2] = livex ? f2b(fmaxf(v.z, 0.f)) : (ushort)0;
        ub[j*4+3] = livex ? f2b(fmaxf(v.w, 0.f)) : (ushort)0;
      }
      int byte = sxr * 256 + ((sxc * 2) ^ ((sxr & 7) << 4));
      *(bf16x8*)((char*)A_lds + byte) = *(bf16x8*)&ub[0];
    }
    {  // stage B: W_in slab transposed (coalesced read along cols)
      ushort ub[32];
#pragma unroll
      for (int j = 0; j < 32; j++)
        ub[j] = f2b(Wn[(size_t)(kt + swq * 32 + j) * SDIM + swc]);
#pragma unroll
      for (int jj = 0; jj < 4; jj++) {
        int byte = swc * 256 + ((swq * 64 + jj * 16) ^ ((swc & 7) << 4));
        *(bf16x8*)((char*)Bi_lds + byte) = *(bf16x8*)&ub[jj * 8];
      }
    }
    __syncthreads();
#pragma unroll
    for (int ks = 0; ks < 4; ks++) {
      bf16x8 bf = *(const bf16x8*)((const char*)Bi_lds +
                    (w * 16 + fr) * 256 + ((ks * 64 + fg * 16) ^ swz));
      bf16x8 af = *(const bf16x8*)((const char*)A_lds +
                    fr * 256 + ((ks * 64 + fg * 16) ^ swz));
      acc = __builtin_amdgcn_mfma_f32_16x16x32_bf16(af, bf, acc, 0, 0, 0);
    }
    __syncthreads();
  }
  int col = w * 16 + fr;
  float bb = b_in[n * SDIM + col];
#pragma unroll
  for (int r = 0; r < 4; r++) {
    int grow = rows[fg * 4 + r];
    if (grow >= 0)
      h_ws[(size_t)grow * SDIM + col] = f2b(acc[r] + bb);
  }
}

// ---------------- K3b: out = x + h @ W_out[sel] + b_out ---------------------
// (round-11-verified single-chunk version; grid 4096)
__global__ __launch_bounds__(256) void k_out2(
    const float* __restrict__ x, const float* __restrict__ W_out,
    const float* __restrict__ b_out, const int* __restrict__ count,
    const int* __restrict__ order, const ushort* __restrict__ h_ws,
    float* __restrict__ out) {
  __shared__ int rows[64];
  __shared__ __align__(16) ushort H_lds[64 * 64];    //  8 KB (lives whole kernel)
  __shared__ __align__(16) char arena[64 * 68 * 4];  // 17408 B: Bo (16384) / Ot
  ushort* Bo_lds = (ushort*)arena;
  float* Ot = (float*)arena;
  int t = threadIdx.x;
  int n = blockIdx.x >> 9;
  int seg = (blockIdx.x >> 3) & 63;
  int cc = (blockIdx.x & 7) * 128;
  int cnt = count[n * CSTRIDE];
  int base = seg * 64;
  if (base >= cnt) return;
  if (t < 64) rows[t] = (base + t < cnt) ? order[n * CAP + base + t] : -1;
  __syncthreads();
  const int l = t & 63, w = t >> 6;
  const int fr = l & 15, fg = l >> 4;
  const int swz = (fr & 7) << 4;
  {  // stage H tile from h_ws (already bf16), swizzled
    int hr = t >> 2;
    int grow = rows[hr];
    const ushort* hp = h_ws + (size_t)(grow >= 0 ? grow : 0) * SDIM + (t & 3) * 16;
    bf16x8 h0 = {}, h1 = {};
    if (grow >= 0) {
      h0 = *(const bf16x8*)hp;
      h1 = *(const bf16x8*)(hp + 8);
    }
    int b0 = hr * 128 + (((t & 3) * 32) ^ ((hr & 7) << 4));
    int b1 = hr * 128 + (((t & 3) * 32 + 16) ^ ((hr & 7) << 4));
    *(bf16x8*)((char*)H_lds + b0) = h0;
    *(bf16x8*)((char*)H_lds + b1) = h1;
  }
  {  // stage W_out chunk transposed (inline f2b — coalesced)
    const float* Wo = W_out + (size_t)n * SDIM * DDIM;
    int scol = t & 127, sh = t >> 7;
    ushort ub[32];
#pragma unroll
    for (int j = 0; j < 32; j++)
      ub[j] = f2b(Wo[(size_t)(sh * 32 + j) * DDIM + cc + scol]);
#pragma unroll
    for (int jj = 0; jj < 4; jj++) {
      int byte = scol * 128 + ((sh * 64 + jj * 16) ^ ((scol & 7) << 4));
      *(bf16x8*)((char*)Bo_lds + byte) = *(bf16x8*)&ub[jj * 8];
    }
  }
  __syncthreads();
  f32x4 acc2[8] = {};
#pragma unroll
  for (int ks = 0; ks < 2; ks++) {
    bf16x8 af = *(const bf16x8*)((const char*)H_lds +
                  (w * 16 + fr) * 128 + ((ks * 64 + fg * 16) ^ swz));
#pragma unroll
    for (int nt = 0; nt < 8; nt++) {
      bf16x8 bf = *(const bf16x8*)((const char*)Bo_lds +
                    (nt * 16 + fr) * 128 + ((ks * 64 + fg * 16) ^ swz));
      acc2[nt] = __builtin_amdgcn_mfma_f32_16x16x32_bf16(af, bf, acc2[nt], 0, 0, 0);
    }
  }
  const float* bo = b_out + n * DDIM + cc;
#pragma unroll
  for (int nt = 0; nt < 8; nt++) {
    float bov = bo[nt * 16 + fr];
#pragma unroll
    for (int r = 0; r < 4; r++) acc2[nt][r] += bov;
  }
  const int orow = t >> 2;            // 0..63
  const int ocol = (t & 3) * 16;      // 0,16,32,48
  const int ogrow = rows[orow];
#pragma unroll
  for (int hh = 0; hh < 2; hh++) {
    __syncthreads();
#pragma unroll
    for (int ntl = 0; ntl < 4; ntl++) {
      int col = ntl * 16 + fr;
#pragma unroll
      for (int r = 0; r < 4; r++)
        Ot[(w * 16 + fg * 4 + r) * 68 + col] = acc2[hh * 4 + ntl][r];
    }
    __syncthreads();
    if (ogrow >= 0) {
      const float* xp = x + (size_t)ogrow * DDIM + cc + hh * 64 + ocol;
      float* op = out + (size_t)ogrow * DDIM + cc + hh * 64 + ocol;
#pragma unroll
      for (int j = 0; j < 4; j++) {
        float4 xx = *(const float4*)&xp[j * 4];
        float4 oo = *(const float4*)&Ot[orow * 68 + ocol + j * 4];
        oo.x += xx.x; oo.y += xx.y; oo.z += xx.z; oo.w += xx.w;
        *(float4*)&op[j * 4] = oo;
      }
    }
  }
}

extern "C" void kernel_launch(void* const* d_in, const int* in_sizes, int n_in,
                              void* d_out, int out_size, void* d_ws, size_t ws_size,
                              hipStream_t stream) {
  const float* x    = (const float*)d_in[0];
  const float* W_in = (const float*)d_in[1];
  const float* b_in = (const float*)d_in[2];
  const float* W_sw = (const float*)d_in[3];
  const float* b_sw = (const float*)d_in[4];
  const float* W_out= (const float*)d_in[5];
  const float* b_out= (const float*)d_in[6];
  float* out0  = (float*)d_out;
  float* ylog  = out0 + (size_t)BROWS * DDIM;
  float* yidx  = ylog + (size_t)BROWS * NBR;
  float* yhard = yidx + (size_t)BROWS;
  char* ws = (char*)d_ws;
  double* v    = (double*)ws;                              // 65536 B
  double* c    = (double*)(ws + 65536);                    // 64 B
  int* count   = (int*)(ws + 65600);                       // 1024 B (8 x 128B)
  int* order   = (int*)(ws + 66624);                       // 524288 B
  ushort* h_ws = (ushort*)(ws + 590912);                   // 2 MB
  double* part = (double*)(ws + 2688064);                  // 4 MB
  hipLaunchKernelGGL(k_fold, dim3(33), dim3(256), 0, stream,
                     W_in, b_in, W_sw, b_sw, v, c, count);
  hipLaunchKernelGGL(k_logits_part, dim3(2048), dim3(256), 0, stream,
                     x, v, part);
  hipLaunchKernelGGL(k_gumbel, dim3(256), dim3(256), 0, stream,
                     part, c, ylog, yidx, yhard, count, order);
  hipLaunchKernelGGL(k_h, dim3(2048), dim3(256), 0, stream,
                     x, W_in, b_in, count, order, h_ws);
  hipLaunchKernelGGL(k_out2, dim3(4096), dim3(256), 0, stream,
                     x, W_out, b_out, count, order, h_ws, out0);
}